// Round 1
// baseline (74.110 us; speedup 1.0000x reference)
//
#include <hip/hip_runtime.h>

// BlockLinear: y[r, c*3+o] = sum_i x[r, c*3+i] * W[c*9 + o*3 + i] + b[c*3+o]
// B=16384 rows, IN_FEATURES=3072, C=1024 components of 3x3 Linear each.
// Memory-bound streaming kernel: ~402 MB total HBM traffic, floor ~64 us.

#define NROWS      16384
#define INF        3072
#define NCOMP      1024
#define ROWS_PER_T 8

struct f3 { float a, b, c; };  // 12-byte chunk, 4B-aligned

__global__ __launch_bounds__(256)
void block_linear_kernel(const float* __restrict__ x,
                         const float* __restrict__ W,
                         const float* __restrict__ bias,
                         float* __restrict__ out) {
    const int tid = blockIdx.x * blockDim.x + threadIdx.x;
    const int c   = tid & (NCOMP - 1);   // component index; consecutive lanes -> consecutive c
    const int rg  = tid >> 10;           // row group, 0 .. NROWS/ROWS_PER_T - 1

    // Load this component's 3x3 weight + bias once; reuse for ROWS_PER_T rows.
    const float* w = W + c * 9;
    const float w00 = w[0], w01 = w[1], w02 = w[2];
    const float w10 = w[3], w11 = w[4], w12 = w[5];
    const float w20 = w[6], w21 = w[7], w22 = w[8];
    const float* bp = bias + c * 3;
    const float b0 = bp[0], b1 = bp[1], b2 = bp[2];

    const int r0 = rg * ROWS_PER_T;
    #pragma unroll
    for (int k = 0; k < ROWS_PER_T; ++k) {
        const size_t off = (size_t)(r0 + k) * INF + (size_t)c * 3;
        f3 v = *reinterpret_cast<const f3*>(x + off);
        f3 y;
        y.a = fmaf(w00, v.a, fmaf(w01, v.b, fmaf(w02, v.c, b0)));
        y.b = fmaf(w10, v.a, fmaf(w11, v.b, fmaf(w12, v.c, b1)));
        y.c = fmaf(w20, v.a, fmaf(w21, v.b, fmaf(w22, v.c, b2)));
        *reinterpret_cast<f3*>(out + off) = y;
    }
}

extern "C" void kernel_launch(void* const* d_in, const int* in_sizes, int n_in,
                              void* d_out, int out_size, void* d_ws, size_t ws_size,
                              hipStream_t stream) {
    const float* x = (const float*)d_in[0];
    const float* W = (const float*)d_in[1];
    const float* b = (const float*)d_in[2];
    float* out = (float*)d_out;

    const int total_threads = (NROWS / ROWS_PER_T) * NCOMP;  // 2,097,152
    const int block = 256;
    const int grid = total_threads / block;                  // 8192
    block_linear_kernel<<<grid, block, 0, stream>>>(x, W, b, out);
}